// Round 7
// baseline (2234.144 us; speedup 1.0000x reference)
//
#include <hip/hip_runtime.h>
#include <hip/hip_bf16.h>
#include <cstdint>

#define N_TOK 16384
#define DMODEL 2048
#define FFH    3072
#define NEXP   8
#define ATOT   32768       // N_TOK * TOP_K

typedef __bf16 bf16;
typedef __attribute__((ext_vector_type(8))) __bf16 bf16x8;
typedef __attribute__((ext_vector_type(4))) __bf16 bf16x4;
typedef __attribute__((ext_vector_type(4))) float  f32x4;

__device__ __forceinline__ void gl_lds16(const bf16* g, void* l) {
  __builtin_amdgcn_global_load_lds(
      (const __attribute__((address_space(1))) void*)g,
      (__attribute__((address_space(3))) void*)l, 16, 0, 0);
}

// ---------------- fp32 -> bf16 conversion (used for down_w only) ----------------
__global__ void cvt_f32_bf16(const float* __restrict__ src, bf16* __restrict__ dst, long n4) {
  long i = (long)blockIdx.x * blockDim.x + threadIdx.x;
  if (i >= n4) return;
  const float4 v = ((const float4*)src)[i];
  bf16x4 o;
  o.x = (bf16)v.x; o.y = (bf16)v.y; o.z = (bf16)v.z; o.w = (bf16)v.w;
  ((bf16x4*)dst)[i] = o;
}

// ------- router fused with x->bf16 conversion: logits, top-2, weights, xb -------
__global__ void router_k(const float* __restrict__ x, const float* __restrict__ rw,
                         bf16* __restrict__ xb,
                         int* __restrict__ tk_e, float* __restrict__ tk_w,
                         int* __restrict__ cnt) {
  const int wv = threadIdx.x >> 6, lane = threadIdx.x & 63;
  const int t = blockIdx.x * 4 + wv;
  const float4* xr = (const float4*)(x + (size_t)t * DMODEL);
  bf16x4* xbr = (bf16x4*)(xb + (size_t)t * DMODEL);
  float acc[NEXP];
#pragma unroll
  for (int e = 0; e < NEXP; ++e) acc[e] = 0.f;
#pragma unroll
  for (int it = 0; it < DMODEL / 4 / 64; ++it) {
    const int idx = lane + it * 64;
    const float4 v = xr[idx];
    bf16x4 o;
    o.x = (bf16)v.x; o.y = (bf16)v.y; o.z = (bf16)v.z; o.w = (bf16)v.w;
    xbr[idx] = o;
#pragma unroll
    for (int e = 0; e < NEXP; ++e) {
      const float4 w = ((const float4*)(rw + e * DMODEL))[idx];
      acc[e] = fmaf(v.x, w.x, fmaf(v.y, w.y, fmaf(v.z, w.z, fmaf(v.w, w.w, acc[e]))));
    }
  }
#pragma unroll
  for (int e = 0; e < NEXP; ++e) {
#pragma unroll
    for (int o = 32; o; o >>= 1) acc[e] += __shfl_xor(acc[e], o, 64);
  }
  if (lane == 0) {
    int e0 = 0; float v0 = acc[0];
#pragma unroll
    for (int e = 1; e < NEXP; ++e) if (acc[e] > v0) { v0 = acc[e]; e0 = e; }
    int e1 = -1; float v1 = -1e30f;
#pragma unroll
    for (int e = 0; e < NEXP; ++e) if (e != e0 && acc[e] > v1) { v1 = acc[e]; e1 = e; }
    const float w0 = 1.f / (1.f + __expf(v1 - v0));
    tk_e[t * 2] = e0; tk_e[t * 2 + 1] = e1;
    tk_w[t * 2] = w0; tk_w[t * 2 + 1] = 1.f - w0;
    atomicAdd(&cnt[e0], 1); atomicAdd(&cnt[e1], 1);
  }
}

__global__ void offs_k(const int* __restrict__ cnt, int* __restrict__ offs) {
  if (threadIdx.x == 0) {
    int o = 0;
    for (int e = 0; e < NEXP; ++e) { offs[e] = o; o += cnt[e]; }
  }
}

__global__ void scatter_k(const int* __restrict__ tk_e, const float* __restrict__ tk_w,
                          const int* __restrict__ offs, int* __restrict__ cnt2,
                          int* __restrict__ tok_list, float* __restrict__ w_list,
                          int* __restrict__ aidx) {
  const int t = blockIdx.x * 256 + threadIdx.x;
  if (t >= N_TOK) return;
#pragma unroll
  for (int k = 0; k < 2; ++k) {
    const int e = tk_e[t * 2 + k];
    const int p = atomicAdd(&cnt2[e], 1);
    const int a = offs[e] + p;
    tok_list[a] = t;
    w_list[a] = tk_w[t * 2 + k];
    aidx[t * 2 + k] = a;
  }
}

// ---- GEMM1: 128x256x32 3-buffer, A=xb gathered (gl_lds), B=gate/up f32 staged
//      via regs+cvt+swizzled ds_write (no pre-converted weight buffer needed).
//      gate/up interleave done at staging: B row R (0..6143): hb=R>>6, sub=R&63,
//      sub<32 -> gate[hb*32+sub] else up[hb*32+sub-32]; wave n-stripe 64 cols =
//      [32 gate | 32 up] so silu(g)*u is register-local in the epilogue.
// Race invariants: A staged 2 tiles ahead (gl_lds, explicit vmcnt(1) covers it);
// B f32 loaded at window start, cvt+ds_written 1 tile ahead mid-window (register
// dependency makes the compiler wait the glb loads); lgkmcnt(0)+barrier per
// window publishes ds_writes. Write targets are buffers whose readers finished
// >=1 barrier ago (3-buffer cycle). LDS swizzle proven r3 (conflicts=0):
// chunk ^= (row>>1)&3 on both write and read addresses.
__global__ __launch_bounds__(512, 2) void gemm_gu(
    const bf16* __restrict__ xb, const float* __restrict__ gw, const float* __restrict__ uw,
    bf16* __restrict__ hbuf, const int* __restrict__ tok_list,
    const int* __restrict__ cnt, const int* __restrict__ offs) {
  constexpr int NT = DMODEL / 32;            // 64 K-tiles
  const int e = blockIdx.z;
  const int cn = cnt[e];
  // XCD-aware swizzle: HW linear id % 8 = XCD; give each XCD a contiguous
  // n-chunk (3 n-tiles) x all m -> B panel L2-resident, balanced live work.
  const int gy = gridDim.y;
  const int flat = blockIdx.x + gridDim.x * blockIdx.y;
  const int q = (gridDim.x * gy) >> 3;
  const int flat2 = (flat & 7) * q + (flat >> 3);
  const int nbt = flat2 / gy;
  const int mbase = (flat2 - nbt * gy) * 128;
  if (mbase >= cn) return;
  const int offE = offs[e];
  const int nbase = nbt * 256;

  __shared__ char lds[73728];                // A: 3x8KB @0, B: 3x16KB @24576
  char* const ldsA = lds;
  char* const ldsB = lds + 24576;

  const int tid = threadIdx.x;
  const int wv = tid >> 6, lane = tid & 63;
  const int wr = wv >> 2, wc = wv & 3;

  const int sr = tid >> 2;                   // 0..127
  const int c4 = tid & 3;
  // A: pre-swizzled global source, linear LDS dest (gl_lds)
  const int swz8 = (c4 ^ ((tid >> 3) & 3)) * 8;
  const int t0 = tok_list[offE + min(mbase + sr, cn - 1)];
  const bf16* pA = xb + (size_t)t0 * DMODEL + swz8;
  const int stageDst = wv * 1024;

  // B: f32 sources for tile rows sr and sr+128, natural chunk c4
  const int R0 = nbase + sr, R1 = nbase + sr + 128;
  const float* pB0 = ((R0 & 63) < 32 ? gw : uw) +
      ((size_t)e * FFH + (R0 >> 6) * 32 + (R0 & 31)) * DMODEL + c4 * 8;
  const float* pB1 = ((R1 & 63) < 32 ? gw : uw) +
      ((size_t)e * FFH + (R1 >> 6) * 32 + (R1 & 31)) * DMODEL + c4 * 8;
  // swizzled ds_write offsets ((sr+128)>>1 & 3 == (sr>>1)&3)
  const int wchunk = (c4 ^ ((sr >> 1) & 3)) * 16;
  const int woff0 = sr * 64 + wchunk;
  const int woff1 = (sr + 128) * 64 + wchunk;

  // ds_read addresses (swizzle matches write image)
  const int rswz = ((lane >> 4) ^ ((lane >> 1) & 3)) * 16;
  const int arow = (wr * 64 + (lane & 15)) * 64 + rswz;
  const int brow = (wc * 64 + (lane & 15)) * 64 + rswz;

  const f32x4 zero = {0.f, 0.f, 0.f, 0.f};
  f32x4 acc[4][4];
#pragma unroll
  for (int i = 0; i < 4; ++i)
#pragma unroll
    for (int j = 0; j < 4; ++j) acc[i][j] = zero;

  auto writeB = [&](int buf, const float4& a0, const float4& a1,
                    const float4& b0, const float4& b1) {
    bf16x8 w0, w1;
    w0[0] = (bf16)a0.x; w0[1] = (bf16)a0.y; w0[2] = (bf16)a0.z; w0[3] = (bf16)a0.w;
    w0[4] = (bf16)a1.x; w0[5] = (bf16)a1.y; w0[6] = (bf16)a1.z; w0[7] = (bf16)a1.w;
    w1[0] = (bf16)b0.x; w1[1] = (bf16)b0.y; w1[2] = (bf16)b0.z; w1[3] = (bf16)b0.w;
    w1[4] = (bf16)b1.x; w1[5] = (bf16)b1.y; w1[6] = (bf16)b1.z; w1[7] = (bf16)b1.w;
    *(bf16x8*)(ldsB + buf * 16384 + woff0) = w0;
    *(bf16x8*)(ldsB + buf * 16384 + woff1) = w1;
  };

  // ---- prologue: B(0) via regs; A(0),A(1) via gl_lds ----
  {
    const float4 n0 = ((const float4*)pB0)[0];
    const float4 n1 = ((const float4*)pB0)[1];
    const float4 n2 = ((const float4*)pB1)[0];
    const float4 n3 = ((const float4*)pB1)[1];
    gl_lds16(pA, ldsA + stageDst);
    gl_lds16(pA + 32, ldsA + 8192 + stageDst);
    writeB(0, n0, n1, n2, n3);                         // implicit vmcnt wait on n*
    asm volatile("s_waitcnt vmcnt(1)" ::: "memory");   // A(0) landed, A(1) in flight
    asm volatile("s_waitcnt lgkmcnt(0)" ::: "memory"); // B(0) writes visible
  }
  __builtin_amdgcn_s_barrier();
  asm volatile("" ::: "memory");

  int cb = 0;
  for (int kt = 0; kt < NT; ++kt) {
    const int nb1 = (cb + 1 == 3) ? 0 : cb + 1;        // buf for tile kt+1 (B write)
    const int nb2 = (nb1 + 1 == 3) ? 0 : nb1 + 1;      // buf for tile kt+2 (A stage)
    const char* cA = ldsA + cb * 8192;
    const char* cB = ldsB + cb * 16384;

    // issue next-tile B f32 loads first (so their implicit wait excludes A)
    float4 n0, n1, n2, n3;
    const bool pf1 = (kt + 1 < NT);
    if (pf1) {
      const float* s0 = pB0 + (kt + 1) * 32;
      const float* s1 = pB1 + (kt + 1) * 32;
      n0 = ((const float4*)s0)[0]; n1 = ((const float4*)s0)[1];
      n2 = ((const float4*)s1)[0]; n3 = ((const float4*)s1)[1];
    }
    if (kt + 2 < NT) gl_lds16(pA + (kt + 2) * 32, ldsA + nb2 * 8192 + stageDst);

    bf16x8 a[4], b01[2], b23[2];
#pragma unroll
    for (int i = 0; i < 4; ++i) a[i] = *(const bf16x8*)(cA + i * 1024 + arow);
#pragma unroll
    for (int i = 0; i < 2; ++i) b01[i] = *(const bf16x8*)(cB + i * 1024 + brow);

    __builtin_amdgcn_s_setprio(1);
#pragma unroll
    for (int nf = 0; nf < 2; ++nf)
#pragma unroll
      for (int mi = 0; mi < 4; ++mi)
        acc[mi][nf] = __builtin_amdgcn_mfma_f32_16x16x32_bf16(a[mi], b01[nf], acc[mi][nf], 0, 0, 0);
    __builtin_amdgcn_s_setprio(0);

    if (pf1) writeB(nb1, n0, n1, n2, n3);              // waits B glb by reg dep

#pragma unroll
    for (int i = 0; i < 2; ++i) b23[i] = *(const bf16x8*)(cB + (2 + i) * 1024 + brow);
    __builtin_amdgcn_s_setprio(1);
#pragma unroll
    for (int nf = 0; nf < 2; ++nf)
#pragma unroll
      for (int mi = 0; mi < 4; ++mi)
        acc[mi][nf + 2] = __builtin_amdgcn_mfma_f32_16x16x32_bf16(a[mi], b23[nf], acc[mi][nf + 2], 0, 0, 0);
    __builtin_amdgcn_s_setprio(0);

    if (kt + 2 < NT) { asm volatile("s_waitcnt vmcnt(1)" ::: "memory"); }
    else             { asm volatile("s_waitcnt vmcnt(0)" ::: "memory"); }
    asm volatile("s_waitcnt lgkmcnt(0)" ::: "memory");
    __builtin_amdgcn_s_barrier();
    asm volatile("" ::: "memory");

    cb = nb1;
  }

  // ---- epilogue: silu(g)*u -> hbuf bf16 (C/D: col=lane&15, row=(lane>>4)*4+j) ----
  const int col = lane & 15;
  const int rb = mbase + wr * 64 + (lane >> 4) * 4;
  const int hb32 = ((nbase + wc * 64) >> 6) * 32;
#pragma unroll
  for (int mi = 0; mi < 4; ++mi)
#pragma unroll
    for (int j = 0; j < 4; ++j) {
      const int row = rb + mi * 16 + j;
      if (row < cn) {
        bf16* hr = hbuf + (size_t)(offE + row) * FFH + hb32 + col;
#pragma unroll
        for (int k = 0; k < 2; ++k) {
          const float g = acc[mi][k][j], u = acc[mi][k + 2][j];
          hr[k * 16] = (bf16)(g / (1.f + __expf(-g)) * u);
        }
      }
    }
}

// ---- GEMM2: 128x256x32 3-buffer, 1 barrier/K-tile (R4 champion structure),
//      A = hbuf rows (gl_lds), B = dwb bf16 (gl_lds), out -> ybuf fp32.
__global__ __launch_bounds__(512, 2) void gemm_dn(
    const bf16* __restrict__ A, const bf16* __restrict__ B,
    float* __restrict__ ybuf,
    const int* __restrict__ cnt, const int* __restrict__ offs) {
  constexpr int NT = FFH / 32;               // 96
  const int e = blockIdx.z;
  const int cn = cnt[e];
  const int gy = gridDim.y;
  const int flat = blockIdx.x + gridDim.x * blockIdx.y;
  const int q = (gridDim.x * gy) >> 3;
  const int flat2 = (flat & 7) * q + (flat >> 3);
  const int nbt = flat2 / gy;
  const int mbase = (flat2 - nbt * gy) * 128;
  if (mbase >= cn) return;
  const int offE = offs[e];
  const int nbase = nbt * 256;

  __shared__ char lds[73728];
  char* const ldsA = lds;
  char* const ldsB = lds + 24576;

  const int tid = threadIdx.x;
  const int wv = tid >> 6, lane = tid & 63;
  const int wr = wv >> 2, wc = wv & 3;

  const int sr = tid >> 2;
  const int swz8 = ((tid & 3) ^ ((tid >> 3) & 3)) * 8;
  const int a0i = offE + min(mbase + sr, cn - 1);
  const bf16* pA = A + (size_t)a0i * FFH + swz8;
  const bf16* pB0 = B + ((size_t)e * DMODEL + nbase + sr) * FFH + swz8;
  const bf16* pB1 = B + ((size_t)e * DMODEL + nbase + 128 + sr) * FFH + swz8;
  const int stageDst = wv * 1024;

  const int rswz = ((lane >> 4) ^ ((lane >> 1) & 3)) * 16;
  const int arow = (wr * 64 + (lane & 15)) * 64 + rswz;
  const int brow = (wc * 64 + (lane & 15)) * 64 + rswz;

  const f32x4 zero = {0.f, 0.f, 0.f, 0.f};
  f32x4 acc[4][4];
#pragma unroll
  for (int i = 0; i < 4; ++i)
#pragma unroll
    for (int j = 0; j < 4; ++j) acc[i][j] = zero;

  auto stageA = [&](int buf, int kt) {
    gl_lds16(pA + kt * 32, ldsA + buf * 8192 + stageDst);
  };
  auto stageB = [&](int buf, int half, int kt) {
    gl_lds16((half ? pB1 : pB0) + kt * 32, ldsB + buf * 16384 + half * 8192 + stageDst);
  };

  stageA(0, 0); stageB(0, 0, 0); stageB(0, 1, 0);
  stageA(1, 1); stageB(1, 0, 1); stageB(1, 1, 1);
  asm volatile("s_waitcnt vmcnt(3)" ::: "memory");
  __builtin_amdgcn_s_barrier();
  asm volatile("" ::: "memory");

  int cb = 0;
  for (int kt = 0; kt < NT; ++kt) {
    const int sb = (cb + 2 >= 3) ? cb - 1 : cb + 2;
    const char* cA = ldsA + cb * 8192;
    const char* cB = ldsB + cb * 16384;

    bf16x8 a[4], b[4];
#pragma unroll
    for (int i = 0; i < 4; ++i) {
      a[i] = *(const bf16x8*)(cA + i * 1024 + arow);
      b[i] = *(const bf16x8*)(cB + i * 1024 + brow);
    }

    if (kt + 2 < NT) { stageA(sb, kt + 2); stageB(sb, 0, kt + 2); }

    __builtin_amdgcn_s_setprio(1);
#pragma unroll
    for (int nf = 0; nf < 2; ++nf)
#pragma unroll
      for (int mi = 0; mi < 4; ++mi)
        acc[mi][nf] = __builtin_amdgcn_mfma_f32_16x16x32_bf16(a[mi], b[nf], acc[mi][nf], 0, 0, 0);
    __builtin_amdgcn_s_setprio(0);

    if (kt + 2 < NT) { stageB(sb, 1, kt + 2); }

    __builtin_amdgcn_s_setprio(1);
#pragma unroll
    for (int nf = 2; nf < 4; ++nf)
#pragma unroll
      for (int mi = 0; mi < 4; ++mi)
        acc[mi][nf] = __builtin_amdgcn_mfma_f32_16x16x32_bf16(a[mi], b[nf], acc[mi][nf], 0, 0, 0);
    __builtin_amdgcn_s_setprio(0);

    if (kt + 2 < NT) { asm volatile("s_waitcnt vmcnt(3)" ::: "memory"); }
    else             { asm volatile("s_waitcnt vmcnt(0)" ::: "memory"); }
    asm volatile("" ::: "memory");
    __builtin_amdgcn_s_barrier();
    asm volatile("" ::: "memory");

    cb = (cb + 1 == 3) ? 0 : cb + 1;
  }

  const int col = lane & 15;
  const int rb = mbase + wr * 64 + (lane >> 4) * 4;
#pragma unroll
  for (int mi = 0; mi < 4; ++mi)
#pragma unroll
    for (int j = 0; j < 4; ++j) {
      const int row = rb + mi * 16 + j;
      if (row < cn) {
        float* yr = ybuf + (size_t)(offE + row) * DMODEL + nbase + wc * 64 + col;
#pragma unroll
        for (int nf = 0; nf < 4; ++nf) yr[nf * 16] = acc[mi][nf][j];
      }
    }
}

// ---------------- final combine: out[t] = w0*y[a0] + w1*y[a1] ----------------
__global__ void combine_k(const float* __restrict__ ybuf, const int* __restrict__ aidx,
                          const float* __restrict__ tk_w, float* __restrict__ out) {
  const int i = blockIdx.x * 256 + threadIdx.x;
  const int t = i >> 9, c = i & 511;
  const int a0 = aidx[t * 2], a1 = aidx[t * 2 + 1];
  const float w0 = tk_w[t * 2], w1 = tk_w[t * 2 + 1];
  const float4 v0 = ((const float4*)(ybuf + (size_t)a0 * DMODEL))[c];
  const float4 v1 = ((const float4*)(ybuf + (size_t)a1 * DMODEL))[c];
  float4 o;
  o.x = w0 * v0.x + w1 * v1.x;
  o.y = w0 * v0.y + w1 * v1.y;
  o.z = w0 * v0.z + w1 * v1.z;
  o.w = w0 * v0.w + w1 * v1.w;
  ((float4*)(out + (size_t)t * DMODEL))[c] = o;
}

extern "C" void kernel_launch(void* const* d_in, const int* in_sizes, int n_in,
                              void* d_out, int out_size, void* d_ws, size_t ws_size,
                              hipStream_t stream) {
  const float* x  = (const float*)d_in[0];
  const float* rw = (const float*)d_in[1];
  const float* gw = (const float*)d_in[2];
  const float* uw = (const float*)d_in[3];
  const float* dw = (const float*)d_in[4];
  float* out = (float*)d_out;

  char* ws = (char*)d_ws;
  size_t o = 0;
  auto alloc = [&](size_t bytes) {
    void* p = ws + o;
    o = (o + bytes + 255) & ~(size_t)255;
    return p;
  };

  bf16*  xb       = (bf16*)alloc((size_t)N_TOK * DMODEL * 2);         // 67 MB
  float* ybuf     = (float*)alloc((size_t)(ATOT + 256) * DMODEL * 4); // 270 MB
  bf16*  dwb      = (bf16*)alloc((size_t)NEXP * DMODEL * FFH * 2);    // 101 MB
  bf16*  hbuf     = (bf16*)alloc((size_t)(ATOT + 256) * FFH * 2);     // 203 MB
  int*   tok_list = (int*)alloc((ATOT + 256) * 4);
  float* w_list   = (float*)alloc((ATOT + 256) * 4);
  int*   tk_e     = (int*)alloc((size_t)N_TOK * 2 * 4);
  float* tk_w     = (float*)alloc((size_t)N_TOK * 2 * 4);
  int*   aidx     = (int*)alloc((size_t)N_TOK * 2 * 4);
  int*   cnt      = (int*)alloc(64);
  int*   offs     = (int*)alloc(64);
  int*   cnt2     = (int*)alloc(64);

  hipMemsetAsync(cnt, 0, 64, stream);
  hipMemsetAsync(cnt2, 0, 64, stream);

  // routing (+ fused x->bf16)
  router_k<<<N_TOK / 4, 256, 0, stream>>>(x, rw, xb, tk_e, tk_w, cnt);
  offs_k<<<1, 64, 0, stream>>>(cnt, offs);
  scatter_k<<<N_TOK / 256, 256, 0, stream>>>(tk_e, tk_w, offs, cnt2, tok_list, w_list, aidx);

  // down_w -> bf16 (gate/up are consumed as f32 directly by gemm_gu)
  {
    long n4 = (long)NEXP * DMODEL * FFH / 4;
    cvt_f32_bf16<<<(unsigned)(n4 / 256), 256, 0, stream>>>(dw, dwb, n4);
  }

  // expert GEMMs (m-grid covers worst case cn=16384 -> 128 tiles of 128)
  gemm_gu<<<dim3(FFH * 2 / 256, 128, NEXP), 512, 0, stream>>>(
      xb, gw, uw, hbuf, tok_list, cnt, offs);
  gemm_dn<<<dim3(DMODEL / 256, 128, NEXP), 512, 0, stream>>>(
      hbuf, dwb, ybuf, cnt, offs);

  // combine (fully overwrites d_out every call)
  combine_k<<<N_TOK * 512 / 256, 256, 0, stream>>>(ybuf, aidx, tk_w, out);
}

// Round 8
// 1966.207 us; speedup vs baseline: 1.1363x; 1.1363x over previous
//
#include <hip/hip_runtime.h>
#include <hip/hip_bf16.h>
#include <cstdint>

#define N_TOK 16384
#define DMODEL 2048
#define FFH    3072
#define NGU    (2 * FFH)   // 6144 interleaved gate/up rows
#define NEXP   8
#define ATOT   32768       // N_TOK * TOP_K

typedef __bf16 bf16;
typedef __attribute__((ext_vector_type(8))) __bf16 bf16x8;
typedef __attribute__((ext_vector_type(4))) __bf16 bf16x4;
typedef __attribute__((ext_vector_type(4))) float  f32x4;

__device__ __forceinline__ void gl_lds16(const bf16* g, void* l) {
  __builtin_amdgcn_global_load_lds(
      (const __attribute__((address_space(1))) void*)g,
      (__attribute__((address_space(3))) void*)l, 16, 0, 0);
}

// ---------------- fp32 -> bf16 conversion (down_w) ----------------
__global__ void cvt_f32_bf16(const float* __restrict__ src, bf16* __restrict__ dst, long n4) {
  long i = (long)blockIdx.x * blockDim.x + threadIdx.x;
  if (i >= n4) return;
  const float4 v = ((const float4*)src)[i];
  bf16x4 o;
  o.x = (bf16)v.x; o.y = (bf16)v.y; o.z = (bf16)v.z; o.w = (bf16)v.w;
  ((bf16x4*)dst)[i] = o;
}

// ---------------- gate/up -> interleaved bf16 buffer ----------------
// guw row ri (0..6143): hb = ri>>6, sub = ri&63; sub<32 -> gate[hb*32+sub], else up[hb*32+sub-32]
__global__ void cvt_guw(const float* __restrict__ gw, const float* __restrict__ uw,
                        bf16* __restrict__ guw) {
  const long i = (long)blockIdx.x * 256 + threadIdx.x;   // one thread per 8 elems
  const int c8 = (int)(i & 255);                          // 2048/8 chunks
  const long rg = i >> 8;                                 // 0..8*6144-1
  const int e = (int)(rg / NGU);
  const int ri = (int)(rg - (long)e * NGU);
  const int hb = ri >> 6, sub = ri & 63;
  const float* src = (sub < 32 ? gw : uw) + ((size_t)e * FFH + hb * 32 + (sub & 31)) * DMODEL + c8 * 8;
  const float4 v0 = ((const float4*)src)[0];
  const float4 v1 = ((const float4*)src)[1];
  bf16x8 o;
  o[0] = (bf16)v0.x; o[1] = (bf16)v0.y; o[2] = (bf16)v0.z; o[3] = (bf16)v0.w;
  o[4] = (bf16)v1.x; o[5] = (bf16)v1.y; o[6] = (bf16)v1.z; o[7] = (bf16)v1.w;
  *(bf16x8*)(guw + rg * DMODEL + c8 * 8) = o;
}

// ------- router fused with x->bf16 conversion: logits, top-2, weights, xb -------
__global__ void router_k(const float* __restrict__ x, const float* __restrict__ rw,
                         bf16* __restrict__ xb,
                         int* __restrict__ tk_e, float* __restrict__ tk_w,
                         int* __restrict__ cnt) {
  const int wv = threadIdx.x >> 6, lane = threadIdx.x & 63;
  const int t = blockIdx.x * 4 + wv;
  const float4* xr = (const float4*)(x + (size_t)t * DMODEL);
  bf16x4* xbr = (bf16x4*)(xb + (size_t)t * DMODEL);
  float acc[NEXP];
#pragma unroll
  for (int e = 0; e < NEXP; ++e) acc[e] = 0.f;
#pragma unroll
  for (int it = 0; it < DMODEL / 4 / 64; ++it) {
    const int idx = lane + it * 64;
    const float4 v = xr[idx];
    bf16x4 o;
    o.x = (bf16)v.x; o.y = (bf16)v.y; o.z = (bf16)v.z; o.w = (bf16)v.w;
    xbr[idx] = o;
#pragma unroll
    for (int e = 0; e < NEXP; ++e) {
      const float4 w = ((const float4*)(rw + e * DMODEL))[idx];
      acc[e] = fmaf(v.x, w.x, fmaf(v.y, w.y, fmaf(v.z, w.z, fmaf(v.w, w.w, acc[e]))));
    }
  }
#pragma unroll
  for (int e = 0; e < NEXP; ++e) {
#pragma unroll
    for (int o = 32; o; o >>= 1) acc[e] += __shfl_xor(acc[e], o, 64);
  }
  if (lane == 0) {
    int e0 = 0; float v0 = acc[0];
#pragma unroll
    for (int e = 1; e < NEXP; ++e) if (acc[e] > v0) { v0 = acc[e]; e0 = e; }
    int e1 = -1; float v1 = -1e30f;
#pragma unroll
    for (int e = 0; e < NEXP; ++e) if (e != e0 && acc[e] > v1) { v1 = acc[e]; e1 = e; }
    const float w0 = 1.f / (1.f + __expf(v1 - v0));
    tk_e[t * 2] = e0; tk_e[t * 2 + 1] = e1;
    tk_w[t * 2] = w0; tk_w[t * 2 + 1] = 1.f - w0;
    atomicAdd(&cnt[e0], 1); atomicAdd(&cnt[e1], 1);
  }
}

__global__ void offs_k(const int* __restrict__ cnt, int* __restrict__ offs) {
  if (threadIdx.x == 0) {
    int o = 0;
    for (int e = 0; e < NEXP; ++e) { offs[e] = o; o += cnt[e]; }
  }
}

__global__ void scatter_k(const int* __restrict__ tk_e, const float* __restrict__ tk_w,
                          const int* __restrict__ offs, int* __restrict__ cnt2,
                          int* __restrict__ tok_list, float* __restrict__ w_list,
                          int* __restrict__ aidx) {
  const int t = blockIdx.x * 256 + threadIdx.x;
  if (t >= N_TOK) return;
#pragma unroll
  for (int k = 0; k < 2; ++k) {
    const int e = tk_e[t * 2 + k];
    const int p = atomicAdd(&cnt2[e], 1);
    const int a = offs[e] + p;
    tok_list[a] = t;
    w_list[a] = tk_w[t * 2 + k];
    aidx[t * 2 + k] = a;
  }
}

// ---------------- 256x256x32 3-buffer MFMA GEMM, 1 barrier / K-tile ----------------
// (R4 champion structure; R7's f32-staging reverted.)
// EPI=0: A = xb gathered by tok_list, B = guw (N=6144), epilogue silu(g)*u -> hbuf bf16
// EPI=1: A = hbuf (assignment rows), B = dwb (N=2048), epilogue -> ybuf bf16 = w * y
// XCD swizzle: hardware XCD = linear_block_id % 8 (z-major stride gx*gy is 8-divisible),
// so flat2 = (flat&7)*q + flat>>3 gives each XCD a contiguous (n,m) chunk.
// Race invariants (3 buffers, 1 barrier + 1 counted vmcnt per iter): iter t reads
// cb, stages sb = buffer read at t-1 (freed by the end-of-iter barrier; all ds_reads
// consumed by MFMAs before it). vmcnt(4) leaves only tile t+2's 4 loads in flight ->
// tile t+1 landed; barrier publishes. LDS swizzle (conflicts=0 proven r3):
// chunk ^= (row>>1)&3 on both stage-source and ds_read addresses (64B rows: parity
// bit is part of the bank slot, so XOR uses bits above parity).
template<int EPI>
__global__ __launch_bounds__(512, 2) void gemm_moe(
    const bf16* __restrict__ A, const bf16* __restrict__ B,
    bf16* __restrict__ hbuf, bf16* __restrict__ ybuf,
    const int* __restrict__ tok_list, const float* __restrict__ w_list,
    const int* __restrict__ cnt, const int* __restrict__ offs) {
  constexpr int KD = EPI ? FFH : DMODEL;   // K length
  constexpr int NT = KD / 32;              // K-tiles
  constexpr int BROWS = EPI ? DMODEL : NGU;

  const int e = blockIdx.z;
  const int cn = cnt[e];
  const int gy = gridDim.y;
  const int flat = blockIdx.x + gridDim.x * blockIdx.y;
  const int q = (gridDim.x * gy) >> 3;
  const int flat2 = (flat & 7) * q + (flat >> 3);
  const int nbt = flat2 / gy;
  const int mbase = (flat2 - nbt * gy) * 256;
  if (mbase >= cn) return;
  const int offE = offs[e];
  const int nbase = nbt * 256;

  __shared__ char lds[98304];              // A: 3x16KB @0, B: 3x16KB @49152
  char* const ldsA = lds;
  char* const ldsB = lds + 49152;

  const int tid = threadIdx.x;
  const int wv = tid >> 6, lane = tid & 63;
  const int wr = wv >> 2, wc = wv & 3;

  // ---- staging source (per-lane, pre-swizzled chunk) ----
  const int sr = tid >> 2;                              // 0..127 row in half
  const int swz8 = ((tid & 3) ^ ((tid >> 3) & 3)) * 8;  // chunk ^ (row>>1)&3, elems
  const bf16* pA[2]; const bf16* pB[2];
  if (EPI == 0) {
    const int t0 = tok_list[offE + min(mbase + sr, cn - 1)];
    const int t1 = tok_list[offE + min(mbase + 128 + sr, cn - 1)];
    pA[0] = A + (size_t)t0 * KD + swz8;
    pA[1] = A + (size_t)t1 * KD + swz8;
  } else {
    const int a0 = offE + min(mbase + sr, cn - 1);
    const int a1 = offE + min(mbase + 128 + sr, cn - 1);
    pA[0] = A + (size_t)a0 * KD + swz8;
    pA[1] = A + (size_t)a1 * KD + swz8;
  }
  pB[0] = B + ((size_t)e * BROWS + nbase + sr) * KD + swz8;
  pB[1] = B + ((size_t)e * BROWS + nbase + 128 + sr) * KD + swz8;

  const int stageDst = wv * 1024;                       // + half*8192 + buf*16384

  // ---- ds_read addresses (swizzled to match source pre-swizzle) ----
  const int rswz = ((lane >> 4) ^ ((lane >> 1) & 3)) * 16;        // byte
  const int arow = (wr * 128 + (lane & 15)) * 64 + rswz;          // + mi*1024
  const int brow = (wc * 64 + (lane & 15)) * 64 + rswz;           // + nf*1024

  const f32x4 zero = {0.f, 0.f, 0.f, 0.f};
  f32x4 acc[8][4];
#pragma unroll
  for (int i = 0; i < 8; ++i)
#pragma unroll
    for (int j = 0; j < 4; ++j) acc[i][j] = zero;

  auto stage_half = [&](int buf, int qh, int kt) {
    const int k8 = kt * 32;
    if (qh < 2) gl_lds16(pA[qh] + k8, ldsA + buf * 16384 + qh * 8192 + stageDst);
    else        gl_lds16(pB[qh - 2] + k8, ldsB + buf * 16384 + (qh - 2) * 8192 + stageDst);
  };

  // prologue: stage tiles 0 and 1
#pragma unroll
  for (int qh = 0; qh < 4; ++qh) stage_half(0, qh, 0);
#pragma unroll
  for (int qh = 0; qh < 4; ++qh) stage_half(1, qh, 1);
  asm volatile("s_waitcnt vmcnt(4)" ::: "memory");   // tile 0 landed
  __builtin_amdgcn_s_barrier();
  asm volatile("" ::: "memory");

  int cb = 0;
  for (int kt = 0; kt < NT; ++kt) {
    const int sb = (cb + 2 >= 3) ? cb - 1 : cb + 2;  // buffer freed last iter
    const char* cA = ldsA + cb * 16384;
    const char* cB = ldsB + cb * 16384;

    bf16x8 a[8], b[4];
#pragma unroll
    for (int i = 0; i < 4; ++i) {
      a[i] = *(const bf16x8*)(cA + i * 1024 + arow);
      b[i] = *(const bf16x8*)(cB + i * 1024 + brow);
    }
#pragma unroll
    for (int i = 4; i < 8; ++i) a[i] = *(const bf16x8*)(cA + i * 1024 + arow);

    if (kt + 2 < NT) { stage_half(sb, 0, kt + 2); stage_half(sb, 1, kt + 2); }

    __builtin_amdgcn_s_setprio(1);
#pragma unroll
    for (int nf = 0; nf < 4; ++nf)
#pragma unroll
      for (int mi = 0; mi < 4; ++mi)
        acc[mi][nf] = __builtin_amdgcn_mfma_f32_16x16x32_bf16(a[mi], b[nf], acc[mi][nf], 0, 0, 0);
    __builtin_amdgcn_s_setprio(0);

    if (kt + 2 < NT) { stage_half(sb, 2, kt + 2); stage_half(sb, 3, kt + 2); }

    __builtin_amdgcn_s_setprio(1);
#pragma unroll
    for (int nf = 0; nf < 4; ++nf)
#pragma unroll
      for (int mi = 4; mi < 8; ++mi)
        acc[mi][nf] = __builtin_amdgcn_mfma_f32_16x16x32_bf16(a[mi], b[nf], acc[mi][nf], 0, 0, 0);
    __builtin_amdgcn_s_setprio(0);

    if (kt + 2 < NT) { asm volatile("s_waitcnt vmcnt(4)" ::: "memory"); }
    else             { asm volatile("s_waitcnt vmcnt(0)" ::: "memory"); }
    asm volatile("" ::: "memory");
    __builtin_amdgcn_s_barrier();
    asm volatile("" ::: "memory");

    cb = (cb + 1 == 3) ? 0 : cb + 1;
  }

  // ---- epilogue (C/D layout: col = lane&15, row = (lane>>4)*4 + j) ----
  const int col = lane & 15;
  const int rb = mbase + wr * 128 + (lane >> 4) * 4;
  if (EPI == 0) {
    const int hb32 = ((nbase + wc * 64) >> 6) * 32;  // h base for this wave's 64-col stripe
#pragma unroll
    for (int mi = 0; mi < 8; ++mi)
#pragma unroll
      for (int j = 0; j < 4; ++j) {
        const int row = rb + mi * 16 + j;
        if (row < cn) {
          bf16* hr = hbuf + (size_t)(offE + row) * FFH + hb32 + col;
#pragma unroll
          for (int k = 0; k < 2; ++k) {
            const float g = acc[mi][k][j], u = acc[mi][k + 2][j];
            hr[k * 16] = (bf16)(g / (1.f + __expf(-g)) * u);
          }
        }
      }
  } else {
#pragma unroll
    for (int mi = 0; mi < 8; ++mi)
#pragma unroll
      for (int j = 0; j < 4; ++j) {
        const int row = rb + mi * 16 + j;
        if (row < cn) {
          const float wg = w_list[offE + row];
          bf16* yr = ybuf + (size_t)(offE + row) * DMODEL + nbase + wc * 64 + col;
#pragma unroll
          for (int nf = 0; nf < 4; ++nf) yr[nf * 16] = (bf16)(wg * acc[mi][nf][j]);
        }
      }
  }
}

// ---------------- final combine: out[t] = y[a0] + y[a1] (w pre-applied) ----------------
__global__ void combine_k(const bf16* __restrict__ ybuf, const int* __restrict__ aidx,
                          float* __restrict__ out) {
  const int i = blockIdx.x * 256 + threadIdx.x;   // N_TOK*256 threads, 8 elems each
  const int t = i >> 8, c = i & 255;
  const int a0 = aidx[t * 2], a1 = aidx[t * 2 + 1];
  const bf16x8 v0 = ((const bf16x8*)(ybuf + (size_t)a0 * DMODEL))[c];
  const bf16x8 v1 = ((const bf16x8*)(ybuf + (size_t)a1 * DMODEL))[c];
  float4 o0, o1;
  o0.x = (float)v0[0] + (float)v1[0];
  o0.y = (float)v0[1] + (float)v1[1];
  o0.z = (float)v0[2] + (float)v1[2];
  o0.w = (float)v0[3] + (float)v1[3];
  o1.x = (float)v0[4] + (float)v1[4];
  o1.y = (float)v0[5] + (float)v1[5];
  o1.z = (float)v0[6] + (float)v1[6];
  o1.w = (float)v0[7] + (float)v1[7];
  float4* op = (float4*)(out + (size_t)t * DMODEL + c * 8);
  op[0] = o0; op[1] = o1;
}

extern "C" void kernel_launch(void* const* d_in, const int* in_sizes, int n_in,
                              void* d_out, int out_size, void* d_ws, size_t ws_size,
                              hipStream_t stream) {
  const float* x  = (const float*)d_in[0];
  const float* rw = (const float*)d_in[1];
  const float* gw = (const float*)d_in[2];
  const float* uw = (const float*)d_in[3];
  const float* dw = (const float*)d_in[4];
  float* out = (float*)d_out;

  char* ws = (char*)d_ws;
  size_t o = 0;
  auto alloc = [&](size_t bytes) {
    void* p = ws + o;
    o = (o + bytes + 255) & ~(size_t)255;
    return p;
  };

  const size_t guw_bytes  = (size_t)NEXP * NGU * DMODEL * 2;          // 201.3 MB
  const size_t ybuf_bytes = (size_t)(ATOT + 256) * DMODEL * 2;        // 135 MB
  bf16*  xb       = (bf16*)alloc((size_t)N_TOK * DMODEL * 2);         // 67 MB
  void*  uni      = alloc(guw_bytes > ybuf_bytes ? guw_bytes : ybuf_bytes);
  bf16*  guw      = (bf16*)uni;     // live: cvt..gemm1
  bf16*  ybuf     = (bf16*)uni;     // live: gemm2..combine (gemm1 done with guw by then)
  bf16*  dwb      = (bf16*)alloc((size_t)NEXP * DMODEL * FFH * 2);    // 100.7 MB
  bf16*  hbuf     = (bf16*)alloc((size_t)(ATOT + 256) * FFH * 2);     // 202.9 MB
  int*   tok_list = (int*)alloc((ATOT + 256) * 4);
  float* w_list   = (float*)alloc((ATOT + 256) * 4);
  int*   tk_e     = (int*)alloc((size_t)N_TOK * 2 * 4);
  float* tk_w     = (float*)alloc((size_t)N_TOK * 2 * 4);
  int*   aidx     = (int*)alloc((size_t)N_TOK * 2 * 4);
  int*   cnt      = (int*)alloc(64);
  int*   offs     = (int*)alloc(64);
  int*   cnt2     = (int*)alloc(64);

  hipMemsetAsync(cnt, 0, 64, stream);
  hipMemsetAsync(cnt2, 0, 64, stream);

  // routing (+ fused x->bf16)
  router_k<<<N_TOK / 4, 256, 0, stream>>>(x, rw, xb, tk_e, tk_w, cnt);
  offs_k<<<1, 64, 0, stream>>>(cnt, offs);
  scatter_k<<<N_TOK / 256, 256, 0, stream>>>(tk_e, tk_w, offs, cnt2, tok_list, w_list, aidx);

  // weight conversions (bf16 pays off: GEMMs re-read B panels many times)
  cvt_guw<<<(unsigned)((long)NEXP * NGU * DMODEL / 8 / 256), 256, 0, stream>>>(gw, uw, guw);
  {
    long n4 = (long)NEXP * DMODEL * FFH / 4;
    cvt_f32_bf16<<<(unsigned)(n4 / 256), 256, 0, stream>>>(dw, dwb, n4);
  }

  // expert GEMMs (m-grid covers worst case cn=16384 -> 64 tiles of 256; empty exit)
  gemm_moe<0><<<dim3(NGU / 256, 64, NEXP), 512, 0, stream>>>(
      xb, guw, hbuf, nullptr, tok_list, w_list, cnt, offs);
  gemm_moe<1><<<dim3(DMODEL / 256, 64, NEXP), 512, 0, stream>>>(
      hbuf, dwb, nullptr, ybuf, tok_list, w_list, cnt, offs);

  // combine (fully overwrites d_out every call)
  combine_k<<<N_TOK, 256, 0, stream>>>(ybuf, aidx, out);
}

// Round 9
// 1924.807 us; speedup vs baseline: 1.1607x; 1.0215x over previous
//
#include <hip/hip_runtime.h>
#include <hip/hip_bf16.h>
#include <cstdint>

#define N_TOK 16384
#define DMODEL 2048
#define FFH    3072
#define NGU    (2 * FFH)   // 6144 interleaved gate/up rows
#define NEXP   8
#define ATOT   32768       // N_TOK * TOP_K

typedef __bf16 bf16;
typedef __attribute__((ext_vector_type(8))) __bf16 bf16x8;
typedef __attribute__((ext_vector_type(4))) __bf16 bf16x4;
typedef __attribute__((ext_vector_type(4))) float  f32x4;

__device__ __forceinline__ void gl_lds16(const bf16* g, void* l) {
  __builtin_amdgcn_global_load_lds(
      (const __attribute__((address_space(1))) void*)g,
      (__attribute__((address_space(3))) void*)l, 16, 0, 0);
}

// ---------------- fp32 -> bf16 conversion (down_w) ----------------
__global__ void cvt_f32_bf16(const float* __restrict__ src, bf16* __restrict__ dst, long n4) {
  long i = (long)blockIdx.x * blockDim.x + threadIdx.x;
  if (i >= n4) return;
  const float4 v = ((const float4*)src)[i];
  bf16x4 o;
  o.x = (bf16)v.x; o.y = (bf16)v.y; o.z = (bf16)v.z; o.w = (bf16)v.w;
  ((bf16x4*)dst)[i] = o;
}

// ---------------- gate/up -> interleaved bf16 buffer ----------------
// guw row ri (0..6143): hb = ri>>6, sub = ri&63; sub<32 -> gate[hb*32+sub], else up[hb*32+sub-32]
__global__ void cvt_guw(const float* __restrict__ gw, const float* __restrict__ uw,
                        bf16* __restrict__ guw) {
  const long i = (long)blockIdx.x * 256 + threadIdx.x;   // one thread per 8 elems
  const int c8 = (int)(i & 255);                          // 2048/8 chunks
  const long rg = i >> 8;                                 // 0..8*6144-1
  const int e = (int)(rg / NGU);
  const int ri = (int)(rg - (long)e * NGU);
  const int hb = ri >> 6, sub = ri & 63;
  const float* src = (sub < 32 ? gw : uw) + ((size_t)e * FFH + hb * 32 + (sub & 31)) * DMODEL + c8 * 8;
  const float4 v0 = ((const float4*)src)[0];
  const float4 v1 = ((const float4*)src)[1];
  bf16x8 o;
  o[0] = (bf16)v0.x; o[1] = (bf16)v0.y; o[2] = (bf16)v0.z; o[3] = (bf16)v0.w;
  o[4] = (bf16)v1.x; o[5] = (bf16)v1.y; o[6] = (bf16)v1.z; o[7] = (bf16)v1.w;
  *(bf16x8*)(guw + rg * DMODEL + c8 * 8) = o;
}

// ------- router fused with x->bf16 conversion: logits, top-2, weights, xb -------
__global__ void router_k(const float* __restrict__ x, const float* __restrict__ rw,
                         bf16* __restrict__ xb,
                         int* __restrict__ tk_e, float* __restrict__ tk_w,
                         int* __restrict__ cnt) {
  const int wv = threadIdx.x >> 6, lane = threadIdx.x & 63;
  const int t = blockIdx.x * 4 + wv;
  const float4* xr = (const float4*)(x + (size_t)t * DMODEL);
  bf16x4* xbr = (bf16x4*)(xb + (size_t)t * DMODEL);
  float acc[NEXP];
#pragma unroll
  for (int e = 0; e < NEXP; ++e) acc[e] = 0.f;
#pragma unroll
  for (int it = 0; it < DMODEL / 4 / 64; ++it) {
    const int idx = lane + it * 64;
    const float4 v = xr[idx];
    bf16x4 o;
    o.x = (bf16)v.x; o.y = (bf16)v.y; o.z = (bf16)v.z; o.w = (bf16)v.w;
    xbr[idx] = o;
#pragma unroll
    for (int e = 0; e < NEXP; ++e) {
      const float4 w = ((const float4*)(rw + e * DMODEL))[idx];
      acc[e] = fmaf(v.x, w.x, fmaf(v.y, w.y, fmaf(v.z, w.z, fmaf(v.w, w.w, acc[e]))));
    }
  }
#pragma unroll
  for (int e = 0; e < NEXP; ++e) {
#pragma unroll
    for (int o = 32; o; o >>= 1) acc[e] += __shfl_xor(acc[e], o, 64);
  }
  if (lane == 0) {
    int e0 = 0; float v0 = acc[0];
#pragma unroll
    for (int e = 1; e < NEXP; ++e) if (acc[e] > v0) { v0 = acc[e]; e0 = e; }
    int e1 = -1; float v1 = -1e30f;
#pragma unroll
    for (int e = 0; e < NEXP; ++e) if (e != e0 && acc[e] > v1) { v1 = acc[e]; e1 = e; }
    const float w0 = 1.f / (1.f + __expf(v1 - v0));
    tk_e[t * 2] = e0; tk_e[t * 2 + 1] = e1;
    tk_w[t * 2] = w0; tk_w[t * 2 + 1] = 1.f - w0;
    atomicAdd(&cnt[e0], 1); atomicAdd(&cnt[e1], 1);
  }
}

__global__ void offs_k(const int* __restrict__ cnt, int* __restrict__ offs) {
  if (threadIdx.x == 0) {
    int o = 0;
    for (int e = 0; e < NEXP; ++e) { offs[e] = o; o += cnt[e]; }
  }
}

__global__ void scatter_k(const int* __restrict__ tk_e, const float* __restrict__ tk_w,
                          const int* __restrict__ offs, int* __restrict__ cnt2,
                          int* __restrict__ tok_list, float* __restrict__ w_list,
                          int* __restrict__ aidx) {
  const int t = blockIdx.x * 256 + threadIdx.x;
  if (t >= N_TOK) return;
#pragma unroll
  for (int k = 0; k < 2; ++k) {
    const int e = tk_e[t * 2 + k];
    const int p = atomicAdd(&cnt2[e], 1);
    const int a = offs[e] + p;
    tok_list[a] = t;
    w_list[a] = tk_w[t * 2 + k];
    aidx[t * 2 + k] = a;
  }
}

// ---------------- 256x256x32 3-buffer MFMA GEMM core (R4 champion) ----------------
// Natural block mapping (no XCD swizzle: R8 A/B showed swizzle doubles FETCH).
// Race invariants: iter t reads cb, stages sb = buffer read at t-1 (freed by the
// end-of-iter barrier); vmcnt(4) leaves only tile t+2's loads in flight -> tile
// t+1 landed; barrier publishes. LDS swizzle (conflicts=0): chunk ^= (row>>1)&3.

// GEMM1: A = xb gathered by tok_list, B = guw (N=6144), epi silu(g)*u -> hbuf bf16
__global__ __launch_bounds__(512, 2) void gemm_gu(
    const bf16* __restrict__ A, const bf16* __restrict__ B,
    bf16* __restrict__ hbuf, const int* __restrict__ tok_list,
    const int* __restrict__ cnt, const int* __restrict__ offs) {
  constexpr int NT = DMODEL / 32;
  const int e = blockIdx.z;
  const int cn = cnt[e];
  const int mbase = blockIdx.y * 256;
  if (mbase >= cn) return;
  const int offE = offs[e];
  const int nbase = blockIdx.x * 256;

  __shared__ char lds[98304];
  char* const ldsA = lds;
  char* const ldsB = lds + 49152;

  const int tid = threadIdx.x;
  const int wv = tid >> 6, lane = tid & 63;
  const int wr = wv >> 2, wc = wv & 3;

  const int sr = tid >> 2;
  const int swz8 = ((tid & 3) ^ ((tid >> 3) & 3)) * 8;
  const int t0 = tok_list[offE + min(mbase + sr, cn - 1)];
  const int t1 = tok_list[offE + min(mbase + 128 + sr, cn - 1)];
  const bf16* pA[2] = { A + (size_t)t0 * DMODEL + swz8, A + (size_t)t1 * DMODEL + swz8 };
  const bf16* pB[2] = { B + ((size_t)e * NGU + nbase + sr) * DMODEL + swz8,
                        B + ((size_t)e * NGU + nbase + 128 + sr) * DMODEL + swz8 };

  const int stageDst = wv * 1024;
  const int rswz = ((lane >> 4) ^ ((lane >> 1) & 3)) * 16;
  const int arow = (wr * 128 + (lane & 15)) * 64 + rswz;
  const int brow = (wc * 64 + (lane & 15)) * 64 + rswz;

  const f32x4 zero = {0.f, 0.f, 0.f, 0.f};
  f32x4 acc[8][4];
#pragma unroll
  for (int i = 0; i < 8; ++i)
#pragma unroll
    for (int j = 0; j < 4; ++j) acc[i][j] = zero;

  auto stage_half = [&](int buf, int qh, int kt) {
    const int k8 = kt * 32;
    if (qh < 2) gl_lds16(pA[qh] + k8, ldsA + buf * 16384 + qh * 8192 + stageDst);
    else        gl_lds16(pB[qh - 2] + k8, ldsB + buf * 16384 + (qh - 2) * 8192 + stageDst);
  };

#pragma unroll
  for (int qh = 0; qh < 4; ++qh) stage_half(0, qh, 0);
#pragma unroll
  for (int qh = 0; qh < 4; ++qh) stage_half(1, qh, 1);
  asm volatile("s_waitcnt vmcnt(4)" ::: "memory");
  __builtin_amdgcn_s_barrier();
  asm volatile("" ::: "memory");

  int cb = 0;
  for (int kt = 0; kt < NT; ++kt) {
    const int sb = (cb + 2 >= 3) ? cb - 1 : cb + 2;
    const char* cA = ldsA + cb * 16384;
    const char* cB = ldsB + cb * 16384;

    bf16x8 a[8], b[4];
#pragma unroll
    for (int i = 0; i < 4; ++i) {
      a[i] = *(const bf16x8*)(cA + i * 1024 + arow);
      b[i] = *(const bf16x8*)(cB + i * 1024 + brow);
    }
#pragma unroll
    for (int i = 4; i < 8; ++i) a[i] = *(const bf16x8*)(cA + i * 1024 + arow);

    if (kt + 2 < NT) { stage_half(sb, 0, kt + 2); stage_half(sb, 1, kt + 2); }

    __builtin_amdgcn_s_setprio(1);
#pragma unroll
    for (int nf = 0; nf < 4; ++nf)
#pragma unroll
      for (int mi = 0; mi < 4; ++mi)
        acc[mi][nf] = __builtin_amdgcn_mfma_f32_16x16x32_bf16(a[mi], b[nf], acc[mi][nf], 0, 0, 0);
    __builtin_amdgcn_s_setprio(0);

    if (kt + 2 < NT) { stage_half(sb, 2, kt + 2); stage_half(sb, 3, kt + 2); }

    __builtin_amdgcn_s_setprio(1);
#pragma unroll
    for (int nf = 0; nf < 4; ++nf)
#pragma unroll
      for (int mi = 4; mi < 8; ++mi)
        acc[mi][nf] = __builtin_amdgcn_mfma_f32_16x16x32_bf16(a[mi], b[nf], acc[mi][nf], 0, 0, 0);
    __builtin_amdgcn_s_setprio(0);

    if (kt + 2 < NT) { asm volatile("s_waitcnt vmcnt(4)" ::: "memory"); }
    else             { asm volatile("s_waitcnt vmcnt(0)" ::: "memory"); }
    asm volatile("" ::: "memory");
    __builtin_amdgcn_s_barrier();
    asm volatile("" ::: "memory");

    cb = (cb + 1 == 3) ? 0 : cb + 1;
  }

  const int col = lane & 15;
  const int rb = mbase + wr * 128 + (lane >> 4) * 4;
  const int hb32 = ((nbase + wc * 64) >> 6) * 32;
#pragma unroll
  for (int mi = 0; mi < 8; ++mi)
#pragma unroll
    for (int j = 0; j < 4; ++j) {
      const int row = rb + mi * 16 + j;
      if (row < cn) {
        bf16* hr = hbuf + (size_t)(offE + row) * FFH + hb32 + col;
#pragma unroll
        for (int k = 0; k < 2; ++k) {
          const float g = acc[mi][k][j], u = acc[mi][k + 2][j];
          hr[k * 16] = (bf16)(g / (1.f + __expf(-g)) * u);
        }
      }
    }
}

// GEMM2: A = hbuf (assignment rows), B = dwb (N=2048), epi -> ybuf bf16 = w*y
__global__ __launch_bounds__(512, 2) void gemm_dn(
    const bf16* __restrict__ A, const bf16* __restrict__ B,
    bf16* __restrict__ ybuf, const float* __restrict__ w_list,
    const int* __restrict__ cnt, const int* __restrict__ offs) {
  constexpr int NT = FFH / 32;
  const int e = blockIdx.z;
  const int cn = cnt[e];
  const int mbase = blockIdx.y * 256;
  if (mbase >= cn) return;
  const int offE = offs[e];
  const int nbase = blockIdx.x * 256;

  __shared__ char lds[98304];
  char* const ldsA = lds;
  char* const ldsB = lds + 49152;

  const int tid = threadIdx.x;
  const int wv = tid >> 6, lane = tid & 63;
  const int wr = wv >> 2, wc = wv & 3;

  const int sr = tid >> 2;
  const int swz8 = ((tid & 3) ^ ((tid >> 3) & 3)) * 8;
  const int a0 = offE + min(mbase + sr, cn - 1);
  const int a1 = offE + min(mbase + 128 + sr, cn - 1);
  const bf16* pA[2] = { A + (size_t)a0 * FFH + swz8, A + (size_t)a1 * FFH + swz8 };
  const bf16* pB[2] = { B + ((size_t)e * DMODEL + nbase + sr) * FFH + swz8,
                        B + ((size_t)e * DMODEL + nbase + 128 + sr) * FFH + swz8 };

  const int stageDst = wv * 1024;
  const int rswz = ((lane >> 4) ^ ((lane >> 1) & 3)) * 16;
  const int arow = (wr * 128 + (lane & 15)) * 64 + rswz;
  const int brow = (wc * 64 + (lane & 15)) * 64 + rswz;

  const f32x4 zero = {0.f, 0.f, 0.f, 0.f};
  f32x4 acc[8][4];
#pragma unroll
  for (int i = 0; i < 8; ++i)
#pragma unroll
    for (int j = 0; j < 4; ++j) acc[i][j] = zero;

  auto stage_half = [&](int buf, int qh, int kt) {
    const int k8 = kt * 32;
    if (qh < 2) gl_lds16(pA[qh] + k8, ldsA + buf * 16384 + qh * 8192 + stageDst);
    else        gl_lds16(pB[qh - 2] + k8, ldsB + buf * 16384 + (qh - 2) * 8192 + stageDst);
  };

#pragma unroll
  for (int qh = 0; qh < 4; ++qh) stage_half(0, qh, 0);
#pragma unroll
  for (int qh = 0; qh < 4; ++qh) stage_half(1, qh, 1);
  asm volatile("s_waitcnt vmcnt(4)" ::: "memory");
  __builtin_amdgcn_s_barrier();
  asm volatile("" ::: "memory");

  int cb = 0;
  for (int kt = 0; kt < NT; ++kt) {
    const int sb = (cb + 2 >= 3) ? cb - 1 : cb + 2;
    const char* cA = ldsA + cb * 16384;
    const char* cB = ldsB + cb * 16384;

    bf16x8 a[8], b[4];
#pragma unroll
    for (int i = 0; i < 4; ++i) {
      a[i] = *(const bf16x8*)(cA + i * 1024 + arow);
      b[i] = *(const bf16x8*)(cB + i * 1024 + brow);
    }
#pragma unroll
    for (int i = 4; i < 8; ++i) a[i] = *(const bf16x8*)(cA + i * 1024 + arow);

    if (kt + 2 < NT) { stage_half(sb, 0, kt + 2); stage_half(sb, 1, kt + 2); }

    __builtin_amdgcn_s_setprio(1);
#pragma unroll
    for (int nf = 0; nf < 4; ++nf)
#pragma unroll
      for (int mi = 0; mi < 4; ++mi)
        acc[mi][nf] = __builtin_amdgcn_mfma_f32_16x16x32_bf16(a[mi], b[nf], acc[mi][nf], 0, 0, 0);
    __builtin_amdgcn_s_setprio(0);

    if (kt + 2 < NT) { stage_half(sb, 2, kt + 2); stage_half(sb, 3, kt + 2); }

    __builtin_amdgcn_s_setprio(1);
#pragma unroll
    for (int nf = 0; nf < 4; ++nf)
#pragma unroll
      for (int mi = 4; mi < 8; ++mi)
        acc[mi][nf] = __builtin_amdgcn_mfma_f32_16x16x32_bf16(a[mi], b[nf], acc[mi][nf], 0, 0, 0);
    __builtin_amdgcn_s_setprio(0);

    if (kt + 2 < NT) { asm volatile("s_waitcnt vmcnt(4)" ::: "memory"); }
    else             { asm volatile("s_waitcnt vmcnt(0)" ::: "memory"); }
    asm volatile("" ::: "memory");
    __builtin_amdgcn_s_barrier();
    asm volatile("" ::: "memory");

    cb = (cb + 1 == 3) ? 0 : cb + 1;
  }

  const int col = lane & 15;
  const int rb = mbase + wr * 128 + (lane >> 4) * 4;
#pragma unroll
  for (int mi = 0; mi < 8; ++mi)
#pragma unroll
    for (int j = 0; j < 4; ++j) {
      const int row = rb + mi * 16 + j;
      if (row < cn) {
        const float wg = w_list[offE + row];
        bf16* yr = ybuf + (size_t)(offE + row) * DMODEL + nbase + wc * 64 + col;
#pragma unroll
        for (int nf = 0; nf < 4; ++nf) yr[nf * 16] = (bf16)(wg * acc[mi][nf][j]);
      }
    }
}

// ---------------- final combine: out[t] = y[a0] + y[a1] (w pre-applied) ----------------
__global__ void combine_k(const bf16* __restrict__ ybuf, const int* __restrict__ aidx,
                          float* __restrict__ out) {
  const int i = blockIdx.x * 256 + threadIdx.x;   // N_TOK*256 threads, 8 elems each
  const int t = i >> 8, c = i & 255;
  const int a0 = aidx[t * 2], a1 = aidx[t * 2 + 1];
  const bf16x8 v0 = ((const bf16x8*)(ybuf + (size_t)a0 * DMODEL))[c];
  const bf16x8 v1 = ((const bf16x8*)(ybuf + (size_t)a1 * DMODEL))[c];
  float4 o0, o1;
  o0.x = (float)v0[0] + (float)v1[0];
  o0.y = (float)v0[1] + (float)v1[1];
  o0.z = (float)v0[2] + (float)v1[2];
  o0.w = (float)v0[3] + (float)v1[3];
  o1.x = (float)v0[4] + (float)v1[4];
  o1.y = (float)v0[5] + (float)v1[5];
  o1.z = (float)v0[6] + (float)v1[6];
  o1.w = (float)v0[7] + (float)v1[7];
  float4* op = (float4*)(out + (size_t)t * DMODEL + c * 8);
  op[0] = o0; op[1] = o1;
}

extern "C" void kernel_launch(void* const* d_in, const int* in_sizes, int n_in,
                              void* d_out, int out_size, void* d_ws, size_t ws_size,
                              hipStream_t stream) {
  const float* x  = (const float*)d_in[0];
  const float* rw = (const float*)d_in[1];
  const float* gw = (const float*)d_in[2];
  const float* uw = (const float*)d_in[3];
  const float* dw = (const float*)d_in[4];
  float* out = (float*)d_out;

  char* ws = (char*)d_ws;
  size_t o = 0;
  auto alloc = [&](size_t bytes) {
    void* p = ws + o;
    o = (o + bytes + 255) & ~(size_t)255;
    return p;
  };

  const size_t guw_bytes  = (size_t)NEXP * NGU * DMODEL * 2;          // 201.3 MB
  const size_t ybuf_bytes = (size_t)(ATOT + 256) * DMODEL * 2;        // 135 MB
  bf16*  xb       = (bf16*)alloc((size_t)N_TOK * DMODEL * 2);         // 67 MB
  void*  uni      = alloc(guw_bytes > ybuf_bytes ? guw_bytes : ybuf_bytes);
  bf16*  guw      = (bf16*)uni;     // live: cvt..gemm1
  bf16*  ybuf     = (bf16*)uni;     // live: gemm2..combine
  bf16*  dwb      = (bf16*)alloc((size_t)NEXP * DMODEL * FFH * 2);    // 100.7 MB
  bf16*  hbuf     = (bf16*)alloc((size_t)(ATOT + 256) * FFH * 2);     // 202.9 MB
  int*   tok_list = (int*)alloc((ATOT + 256) * 4);
  float* w_list   = (float*)alloc((ATOT + 256) * 4);
  int*   tk_e     = (int*)alloc((size_t)N_TOK * 2 * 4);
  float* tk_w     = (float*)alloc((size_t)N_TOK * 2 * 4);
  int*   aidx     = (int*)alloc((size_t)N_TOK * 2 * 4);
  int*   cnt      = (int*)alloc(64);
  int*   offs     = (int*)alloc(64);
  int*   cnt2     = (int*)alloc(64);

  hipMemsetAsync(cnt, 0, 64, stream);
  hipMemsetAsync(cnt2, 0, 64, stream);

  // routing (+ fused x->bf16)
  router_k<<<N_TOK / 4, 256, 0, stream>>>(x, rw, xb, tk_e, tk_w, cnt);
  offs_k<<<1, 64, 0, stream>>>(cnt, offs);
  scatter_k<<<N_TOK / 256, 256, 0, stream>>>(tk_e, tk_w, offs, cnt2, tok_list, w_list, aidx);

  // weight conversions (bf16 pays off: GEMMs re-read B panels many times)
  cvt_guw<<<(unsigned)((long)NEXP * NGU * DMODEL / 8 / 256), 256, 0, stream>>>(gw, uw, guw);
  {
    long n4 = (long)NEXP * DMODEL * FFH / 4;
    cvt_f32_bf16<<<(unsigned)(n4 / 256), 256, 0, stream>>>(dw, dwb, n4);
  }

  // expert GEMMs (m-grid covers worst case cn=16384 -> 64 tiles of 256; empty exit)
  gemm_gu<<<dim3(NGU / 256, 64, NEXP), 512, 0, stream>>>(
      xb, guw, hbuf, tok_list, cnt, offs);
  gemm_dn<<<dim3(DMODEL / 256, 64, NEXP), 512, 0, stream>>>(
      hbuf, dwb, ybuf, w_list, cnt, offs);

  // combine (fully overwrites d_out every call)
  combine_k<<<N_TOK, 256, 0, stream>>>(ybuf, aidx, out);
}